// Round 16
// baseline (94.410 us; speedup 1.0000x reference)
//
#include <hip/hip_runtime.h>
#include <hip/hip_bf16.h>
#include <math.h>

// Problem dims (fixed by reference)
constexpr int B_ = 128, T_ = 512, I_ = 1024, H_ = 2048, O_ = 512;
#define BETA 0.9f

// ws float layout: y[B*I] | Z[B*H]   (both zeroed via memsetAsync)
constexpr int YOFF = 0;
constexpr int ZOFF = B_ * I_;                  // 131072
constexpr int ZERO_BYTES = (ZOFF + B_ * H_) * 4;  // y + Z = 1.5 MB

typedef __attribute__((ext_vector_type(4))) short short4v;   // 4 bf16
typedef __attribute__((ext_vector_type(8))) short short8v;   // 8 bf16 (4 VGPR)
typedef __attribute__((ext_vector_type(4))) float float4v;   // 4 f32

// ---------------------------------------------------------------------------
// Kernel 1 (R9-body + inline w-table): y[b,i] += sum_{t in chunk} w_t x[b,t,i]
// TCH=128 -> 512 blocks, plain cached float4 loads, 4-way atomics.
// ---------------------------------------------------------------------------
constexpr int TCH = 128;
__global__ __launch_bounds__(256) void wreduce_kernel(const float* __restrict__ x,
                                                      float* __restrict__ ws) {
    __shared__ float wl[TCH];
    const int b  = blockIdx.x >> 2;
    const int tc = blockIdx.x & 3;
    const int t0 = tc * TCH;
    if (threadIdx.x < TCH)           // w[t] = (1-0.9^(T-t))/0.1  (R4-proven inline)
        wl[threadIdx.x] = (1.f - powf(BETA, (float)(T_ - (t0 + threadIdx.x)))) * 10.f;
    __syncthreads();

    const int i = threadIdx.x * 4;
    const float* xp = x + (size_t)b * T_ * I_ + (size_t)t0 * I_ + i;
    float4v acc = {0.f, 0.f, 0.f, 0.f};
#pragma unroll 4
    for (int tb = 0; tb < TCH; tb += 8) {
        float4v v[8];
#pragma unroll
        for (int j = 0; j < 8; ++j)
            v[j] = *(const float4v*)(xp + (size_t)(tb + j) * I_);
#pragma unroll
        for (int j = 0; j < 8; ++j) {
            const float wt = wl[tb + j];
            acc.x += wt * v[j].x; acc.y += wt * v[j].y;
            acc.z += wt * v[j].z; acc.w += wt * v[j].w;
        }
    }
    float* yp = ws + YOFF + b * I_ + i;
    atomicAdd(yp + 0, acc.x);
    atomicAdd(yp + 1, acc.y);
    atomicAdd(yp + 2, acc.z);
    atomicAdd(yp + 3, acc.w);
}

// ---------------------------------------------------------------------------
// Kernel 2/3 (R8/R9-proven body): C[128,N] += A[128,K] @ B[K,N], builtin
// 16x16x32 bf16 MFMA, f32 atomic epilogue. NEW: bias folded into epilogue —
// blocks with blockIdx.y==0 add bscale*bias[col] exactly once.
// grid = (N/64, K/KCH); proven trip counts 4 (mm1) and 2 (mm2).
// ---------------------------------------------------------------------------
template <int KGLOB, int NGLOB, int KCH>
__global__ __launch_bounds__(256) void mm128(const float* __restrict__ A,
                                             const float* __restrict__ Bm,
                                             float* __restrict__ C,
                                             const float* __restrict__ bias,
                                             float bscale) {
    constexpr int BN = 64, BK = 32, PAD = 8;
    __shared__ __align__(16) __hip_bfloat16 As[128][BK + PAD];  // [row][k]
    __shared__ __align__(16) __hip_bfloat16 Bs[BN][BK + PAD];   // [n][k]

    const int n0    = blockIdx.x * BN;
    const int kbase = blockIdx.y * KCH;
    const int tid   = threadIdx.x;
    const int lane  = tid & 63;
    const int w     = tid >> 6;
    const int lo    = lane & 15;
    const int hi    = lane >> 4;

    float4v acc[2][4];
#pragma unroll
    for (int mf = 0; mf < 2; ++mf)
#pragma unroll
        for (int nf = 0; nf < 4; ++nf) acc[mf][nf] = (float4v){0.f, 0.f, 0.f, 0.f};

    for (int k0 = kbase; k0 < kbase + KCH; k0 += BK) {
        {
            const int row = tid >> 1;
            const int kh  = (tid & 1) * 16;
            const float* ap = A + (size_t)row * KGLOB + k0 + kh;
#pragma unroll
            for (int j = 0; j < 4; ++j) {
                float4 v = *(const float4*)(ap + 4 * j);
                union { short4v s; __hip_bfloat16 h[4]; } u;
                u.h[0] = __float2bfloat16(v.x); u.h[1] = __float2bfloat16(v.y);
                u.h[2] = __float2bfloat16(v.z); u.h[3] = __float2bfloat16(v.w);
                *(short4v*)&As[row][kh + 4 * j] = u.s;
            }
        }
        {
            const int k  = tid >> 3;
            const int nq = (tid & 7) * 8;
            const float* bp = Bm + (size_t)(k0 + k) * NGLOB + n0 + nq;
#pragma unroll
            for (int j = 0; j < 2; ++j) {
                float4 v = *(const float4*)(bp + 4 * j);
                Bs[nq + 4 * j + 0][k] = __float2bfloat16(v.x);
                Bs[nq + 4 * j + 1][k] = __float2bfloat16(v.y);
                Bs[nq + 4 * j + 2][k] = __float2bfloat16(v.z);
                Bs[nq + 4 * j + 3][k] = __float2bfloat16(v.w);
            }
        }
        __syncthreads();
        {
            const int kk = hi * 8;
            short8v a[2], bv[4];
#pragma unroll
            for (int mf = 0; mf < 2; ++mf)
                a[mf] = *(const short8v*)&As[w * 32 + mf * 16 + lo][kk];
#pragma unroll
            for (int nf = 0; nf < 4; ++nf)
                bv[nf] = *(const short8v*)&Bs[nf * 16 + lo][kk];
#pragma unroll
            for (int mf = 0; mf < 2; ++mf)
#pragma unroll
                for (int nf = 0; nf < 4; ++nf)
                    acc[mf][nf] = __builtin_amdgcn_mfma_f32_16x16x32_bf16(
                        a[mf], bv[nf], acc[mf][nf], 0, 0, 0);
        }
        __syncthreads();
    }
    const bool addb = (blockIdx.y == 0);
#pragma unroll
    for (int mf = 0; mf < 2; ++mf)
#pragma unroll
        for (int nf = 0; nf < 4; ++nf)
#pragma unroll
            for (int i = 0; i < 4; ++i) {
                const int row = w * 32 + mf * 16 + hi * 4 + i;
                const int col = n0 + nf * 16 + lo;
                float v = acc[mf][nf][i];
                if (addb) v += bscale * bias[col];
                atomicAdd(&C[(size_t)row * NGLOB + col], v);
            }
}

// ---------------------------------------------------------------------------
extern "C" void kernel_launch(void* const* d_in, const int* in_sizes, int n_in,
                              void* d_out, int out_size, void* d_ws, size_t ws_size,
                              hipStream_t stream) {
    const float* x     = (const float*)d_in[0];
    const float* W_in  = (const float*)d_in[1];
    const float* b_in  = (const float*)d_in[2];
    const float* W_out = (const float*)d_in[3];
    const float* b_out = (const float*)d_in[4];
    float* out = (float*)d_out;
    float* ws  = (float*)d_ws;

    // wsum = sum_t (1-beta^(T-t))/(1-beta), exact in double on host
    const double beta = 0.9;
    const double bT = pow(beta, (double)T_);
    const float wsum = (float)(((double)T_ - beta * (1.0 - bT) / (1.0 - beta)) / (1.0 - beta));

    // zero y+Z and out (async memset is graph-capture safe)
    hipMemsetAsync(ws, 0, ZERO_BYTES, stream);
    hipMemsetAsync(out, 0, (size_t)B_ * O_ * 4, stream);

    wreduce_kernel<<<B_ * (T_ / TCH), 256, 0, stream>>>(x, ws);

    // Z = y @ W_in + wsum*b_in : KCH=128 -> 256 blocks, 4 iters (proven)
    mm128<I_, H_, 128><<<dim3(H_ / 64, I_ / 128), 256, 0, stream>>>(
        ws + YOFF, W_in, ws + ZOFF, b_in, wsum);

    // out = Z @ W_out + T*b_out : KCH=64 -> 256 blocks, 2 iters (proven)
    mm128<H_, O_, 64><<<dim3(O_ / 64, H_ / 64), 256, 0, stream>>>(
        ws + ZOFF, W_out, out, b_out, (float)T_);
}

// Round 17
// 75.105 us; speedup vs baseline: 1.2570x; 1.2570x over previous
//
#include <hip/hip_runtime.h>
#include <hip/hip_bf16.h>
#include <math.h>

// Problem dims (fixed by reference)
constexpr int B_ = 128, T_ = 512, I_ = 1024, H_ = 2048, O_ = 512;
#define BETA 0.9f

// ws float layout: w[512] | y[B*I] | Z[B*H]
constexpr int WOFF = 0;
constexpr int YOFF = 512;
constexpr int ZOFF = YOFF + B_ * I_;
constexpr int WS_FLOATS = ZOFF + B_ * H_;

typedef __attribute__((ext_vector_type(4))) short short4v;   // 4 bf16
typedef __attribute__((ext_vector_type(8))) short short8v;   // 8 bf16 (4 VGPR)
typedef __attribute__((ext_vector_type(4))) float float4v;   // 4 f32

// ---------------------------------------------------------------------------
// Kernel 1 (R9-exact): init w[t], zero y, Z = wsum*b_in, out = T*b_out
// ---------------------------------------------------------------------------
__global__ __launch_bounds__(256) void init_kernel(float* __restrict__ ws,
                                                   const float* __restrict__ b_in,
                                                   const float* __restrict__ b_out,
                                                   float* __restrict__ out, float wsum) {
    int idx = blockIdx.x * 256 + threadIdx.x;
    const int total = WS_FLOATS + B_ * O_;
    if (idx >= total) return;
    if (idx < 512) {
        ws[idx] = (1.0f - powf(BETA, (float)(T_ - idx))) * (1.0f / (1.0f - BETA));
    } else if (idx < ZOFF) {
        ws[idx] = 0.0f;                       // y accumulator
    } else if (idx < WS_FLOATS) {
        int j = idx - ZOFF;
        ws[idx] = wsum * b_in[j & (H_ - 1)];  // Z bias init
    } else {
        int j = idx - WS_FLOATS;
        out[j] = (float)T_ * b_out[j & (O_ - 1)];  // out bias init
    }
}

// ---------------------------------------------------------------------------
// Kernel 2: y[b,i] += sum_{t in chunk} w[t] * x[b,t,i]
// TCH=128, 512 blocks. NEW vs R9: wave w owns t-rows [t0+32w, t0+32w+32) and
// reads them FULLY CONTIGUOUSLY (128 KB sequential per wave — DRAM page
// locality); per-wave y-partial in registers, cross-wave LDS reduce, same
// 4-way atomic tail.
// ---------------------------------------------------------------------------
constexpr int TCH = 128;
__global__ __launch_bounds__(256) void wreduce_kernel(const float* __restrict__ x,
                                                      float* __restrict__ ws) {
    __shared__ float wl[TCH];
    __shared__ __align__(16) float red[4 * 256 * 4];   // [wave][256 float4] 16 KB
    const int b  = blockIdx.x >> 2;
    const int tc = blockIdx.x & 3;
    const int t0 = tc * TCH;
    if (threadIdx.x < TCH) wl[threadIdx.x] = ws[WOFF + t0 + threadIdx.x];
    __syncthreads();

    const int w = threadIdx.x >> 6;      // wave 0..3 -> t-rows [32w, 32w+32)
    const int l = threadIdx.x & 63;
    const float* xb = x + (size_t)b * T_ * I_ + (size_t)(t0 + w * 32) * I_ + l * 4;

    float4v acc0 = {0,0,0,0}, acc1 = {0,0,0,0}, acc2 = {0,0,0,0}, acc3 = {0,0,0,0};
#pragma unroll 4
    for (int tt = 0; tt < 32; tt += 2) {     // 2 rows x 4 quarters = 8 loads
        const float* r0 = xb + (size_t)tt * I_;
        float4v v[8];
#pragma unroll
        for (int j = 0; j < 4; ++j) v[j]     = *(const float4v*)(r0 + j * 256);
#pragma unroll
        for (int j = 0; j < 4; ++j) v[4 + j] = *(const float4v*)(r0 + I_ + j * 256);
        const float w0 = wl[w * 32 + tt], w1 = wl[w * 32 + tt + 1];
        acc0 += w0 * v[0] + w1 * v[4];
        acc1 += w0 * v[1] + w1 * v[5];
        acc2 += w0 * v[2] + w1 * v[6];
        acc3 += w0 * v[3] + w1 * v[7];
    }
    // red[w][j*64+l] = acc_j   (i = j*256 + l*4)
    *(float4v*)&red[(w * 256 + 0 * 64 + l) * 4] = acc0;
    *(float4v*)&red[(w * 256 + 1 * 64 + l) * 4] = acc1;
    *(float4v*)&red[(w * 256 + 2 * 64 + l) * 4] = acc2;
    *(float4v*)&red[(w * 256 + 3 * 64 + l) * 4] = acc3;
    __syncthreads();
    {
        const int s = threadIdx.x;           // slot 0..255
        float4v r = *(const float4v*)&red[(0 * 256 + s) * 4]
                  + *(const float4v*)&red[(1 * 256 + s) * 4]
                  + *(const float4v*)&red[(2 * 256 + s) * 4]
                  + *(const float4v*)&red[(3 * 256 + s) * 4];
        const int i = (s >> 6) * 256 + (s & 63) * 4;
        float* yp = ws + YOFF + (size_t)b * I_ + i;
        atomicAdd(yp + 0, r.x);
        atomicAdd(yp + 1, r.y);
        atomicAdd(yp + 2, r.z);
        atomicAdd(yp + 3, r.w);
    }
}

// ---------------------------------------------------------------------------
// Kernel 3/4 (R8/R9-proven, verbatim): C[128,N] += A[128,K] @ B[K,N],
// builtin 16x16x32 bf16 MFMA, f32 atomic epilogue. grid = (N/64, K/KCH).
// ---------------------------------------------------------------------------
template <int KGLOB, int NGLOB, int KCH>
__global__ __launch_bounds__(256) void mm128(const float* __restrict__ A,
                                             const float* __restrict__ Bm,
                                             float* __restrict__ C) {
    constexpr int BN = 64, BK = 32, PAD = 8;
    __shared__ __align__(16) __hip_bfloat16 As[128][BK + PAD];  // [row][k]
    __shared__ __align__(16) __hip_bfloat16 Bs[BN][BK + PAD];   // [n][k]

    const int n0    = blockIdx.x * BN;
    const int kbase = blockIdx.y * KCH;
    const int tid   = threadIdx.x;
    const int lane  = tid & 63;
    const int w     = tid >> 6;
    const int lo    = lane & 15;
    const int hi    = lane >> 4;

    float4v acc[2][4];
#pragma unroll
    for (int mf = 0; mf < 2; ++mf)
#pragma unroll
        for (int nf = 0; nf < 4; ++nf) acc[mf][nf] = (float4v){0.f, 0.f, 0.f, 0.f};

    for (int k0 = kbase; k0 < kbase + KCH; k0 += BK) {
        {
            const int row = tid >> 1;
            const int kh  = (tid & 1) * 16;
            const float* ap = A + (size_t)row * KGLOB + k0 + kh;
#pragma unroll
            for (int j = 0; j < 4; ++j) {
                float4 v = *(const float4*)(ap + 4 * j);
                union { short4v s; __hip_bfloat16 h[4]; } u;
                u.h[0] = __float2bfloat16(v.x); u.h[1] = __float2bfloat16(v.y);
                u.h[2] = __float2bfloat16(v.z); u.h[3] = __float2bfloat16(v.w);
                *(short4v*)&As[row][kh + 4 * j] = u.s;
            }
        }
        {
            const int k  = tid >> 3;
            const int nq = (tid & 7) * 8;
            const float* bp = Bm + (size_t)(k0 + k) * NGLOB + n0 + nq;
#pragma unroll
            for (int j = 0; j < 2; ++j) {
                float4 v = *(const float4*)(bp + 4 * j);
                Bs[nq + 4 * j + 0][k] = __float2bfloat16(v.x);
                Bs[nq + 4 * j + 1][k] = __float2bfloat16(v.y);
                Bs[nq + 4 * j + 2][k] = __float2bfloat16(v.z);
                Bs[nq + 4 * j + 3][k] = __float2bfloat16(v.w);
            }
        }
        __syncthreads();
        {
            const int kk = hi * 8;
            short8v a[2], bv[4];
#pragma unroll
            for (int mf = 0; mf < 2; ++mf)
                a[mf] = *(const short8v*)&As[w * 32 + mf * 16 + lo][kk];
#pragma unroll
            for (int nf = 0; nf < 4; ++nf)
                bv[nf] = *(const short8v*)&Bs[nf * 16 + lo][kk];
#pragma unroll
            for (int mf = 0; mf < 2; ++mf)
#pragma unroll
                for (int nf = 0; nf < 4; ++nf)
                    acc[mf][nf] = __builtin_amdgcn_mfma_f32_16x16x32_bf16(
                        a[mf], bv[nf], acc[mf][nf], 0, 0, 0);
        }
        __syncthreads();
    }
#pragma unroll
    for (int mf = 0; mf < 2; ++mf)
#pragma unroll
        for (int nf = 0; nf < 4; ++nf)
#pragma unroll
            for (int i = 0; i < 4; ++i) {
                const int row = w * 32 + mf * 16 + hi * 4 + i;
                const int col = n0 + nf * 16 + lo;
                atomicAdd(&C[(size_t)row * NGLOB + col], acc[mf][nf][i]);
            }
}

// ---------------------------------------------------------------------------
extern "C" void kernel_launch(void* const* d_in, const int* in_sizes, int n_in,
                              void* d_out, int out_size, void* d_ws, size_t ws_size,
                              hipStream_t stream) {
    const float* x     = (const float*)d_in[0];
    const float* W_in  = (const float*)d_in[1];
    const float* b_in  = (const float*)d_in[2];
    const float* W_out = (const float*)d_in[3];
    const float* b_out = (const float*)d_in[4];
    float* out = (float*)d_out;
    float* ws  = (float*)d_ws;

    // wsum = sum_t (1-beta^(T-t))/(1-beta), exact in double on host
    const double beta = 0.9;
    const double bT = pow(beta, (double)T_);
    const float wsum = (float)(((double)T_ - beta * (1.0 - bT) / (1.0 - beta)) / (1.0 - beta));

    const int total = WS_FLOATS + B_ * O_;
    init_kernel<<<(total + 255) / 256, 256, 0, stream>>>(ws, b_in, b_out, out, wsum);

    wreduce_kernel<<<B_ * (T_ / TCH), 256, 0, stream>>>(x, ws);

    // Z = y @ W_in : K=1024, split-K 8 (KCH=128) -> 256 blocks, 4 iters each
    mm128<I_, H_, 128><<<dim3(H_ / 64, I_ / 128), 256, 0, stream>>>(ws + YOFF, W_in, ws + ZOFF);

    // out = Z @ W_out : K=2048, split-K 32 (KCH=64) -> 256 blocks, 2 iters each
    mm128<H_, O_, 64><<<dim3(O_ / 64, H_ / 64), 256, 0, stream>>>(ws + ZOFF, W_out, out);
}